// Round 5
// baseline (380.746 us; speedup 1.0000x reference)
//
#include <hip/hip_runtime.h>

// Problem constants (match reference)
constexpr int Bx = 64;
constexpr int Lx = 1024;
constexpr int Dx = 1024;
constexpr int Sx = 32;

constexpr int DC   = 128;             // D-columns per block
constexpr int NCH  = Dx / DC;         // 8 chunks
constexpr int NBLK = Bx * NCH;        // 512 blocks, 512 thr = 2 blocks/CU

typedef __attribute__((ext_vector_type(8))) short bf16x8;  // 8 bf16 (4 VGPRs)
typedef __attribute__((ext_vector_type(4))) float f32x4;   // MFMA C/D frag

// ---------------------------------------------------------------------------
// Kernel 0: per-batch label histogram -> wcnt[b][s]
// ---------------------------------------------------------------------------
__global__ __launch_bounds__(1024) void hist_kernel(
    const int* __restrict__ attrs, int* __restrict__ wcnt)
{
    __shared__ int hist[Sx + 1];
    const int b = blockIdx.x, tid = threadIdx.x;
    if (tid <= Sx) hist[tid] = 0;
    __syncthreads();
    atomicAdd(&hist[attrs[b * Lx + tid]], 1);
    __syncthreads();
    if (tid >= 1 && tid <= Sx) wcnt[b * Sx + (tid - 1)] = hist[tid];
}

// ---------------------------------------------------------------------------
// Kernel 1: seg_sum via MFMA with on-the-fly one-hot A operand.
//  Block = (batch, 128-col d-chunk), 512 threads = 8 waves, wave w owns
//  n-tile d0+w*16. K = L = 1024 tokens, 32 k-steps of 32.
//  A[m][k] = (attrs[l0+k] == m+1) as bf16 1.0/0.0, built in VGPRs from an
//    LDS-staged attrs row (broadcast reads, no conflicts).
//  B[k][n] = text[l0+k][dcol] loaded DIRECTLY from global: per load instr
//    each quad reads 64 B contiguous; l advances sequentially -> DRAM-page
//    friendly (the round-2..4 sorted gather was a random-1KB-granule stream,
//    ~3 TB/s; this is the fix). fp32 -> bf16 hi+lo exact split, both
//    accumulated into the same C frag (C += A*Bhi + A*Blo).
//  Epilogue: C[label][dcol] partials -> dot with Vgs, norms; quad-level
//    shfl reduce -> LDS -> pnum/pns2/pnv2[bid][s] (additive across chunks).
// ---------------------------------------------------------------------------
__global__ __launch_bounds__(512, 4) void seg_dot_kernel(
    const float* __restrict__ text,    // [B][L][D]
    const float* __restrict__ vgs,     // [B][S][D]
    const int*   __restrict__ attrs,   // [B][L]
    float* __restrict__ pnum,          // [NBLK][S]
    float* __restrict__ pns2,          // [NBLK][S]
    float* __restrict__ pnv2)          // [NBLK][S]
{
    __shared__ int   attrs_lds[Lx];    // 4 KB
    __shared__ float red[3 * Sx];

    const int tid   = threadIdx.x;
    const int bid   = blockIdx.x;
    const int b     = bid >> 3;
    const int chunk = bid & 7;
    const int d0    = chunk * DC;
    const int w     = tid >> 6;
    const int lane  = tid & 63;
    const int quad  = lane >> 4;
    const int m     = lane & 15;       // A row / C col / B col index

    attrs_lds[tid]       = attrs[b * Lx + tid];
    attrs_lds[tid + 512] = attrs[b * Lx + tid + 512];
    for (int i = tid; i < 3 * Sx; i += 512) red[i] = 0.0f;
    __syncthreads();

    const int dcol = d0 + w * 16 + m;  // this lane's d column
    const float* __restrict__ tp = text + (size_t)b * Lx * Dx + dcol;

    f32x4 acc0 = {0.f, 0.f, 0.f, 0.f};  // labels 1..16  (m-tile 0)
    f32x4 acc1 = {0.f, 0.f, 0.f, 0.f};  // labels 17..32 (m-tile 1)

    float buf[2][8];
    #pragma unroll
    for (int j = 0; j < 8; ++j)        // prologue: k-step 0 loads
        buf[0][j] = tp[(size_t)(quad * 8 + j) * Dx];

    #pragma unroll
    for (int ks = 0; ks < 32; ++ks) {
        const int cb = ks & 1, nb = cb ^ 1;
        if (ks < 31) {                 // prefetch next k-step (8 in flight)
            const int l1 = (ks + 1) * 32 + quad * 8;
            #pragma unroll
            for (int j = 0; j < 8; ++j)
                buf[nb][j] = tp[(size_t)(l1 + j) * Dx];
        }
        // A frags: one-hot vs this lane's labels (m+1, m+17)
        const int lb = ks * 32 + quad * 8;
        bf16x8 a0, a1;
        #pragma unroll
        for (int j = 0; j < 8; ++j) {
            const int av = attrs_lds[lb + j];          // quad-broadcast read
            a0[j] = (av == m + 1)  ? (short)0x3F80 : (short)0;
            a1[j] = (av == m + 17) ? (short)0x3F80 : (short)0;
        }
        // B frags: exact fp32 = bf16_hi + ~bf16_lo split
        bf16x8 bh, bl;
        #pragma unroll
        for (int j = 0; j < 8; ++j) {
            const float    f  = buf[cb][j];
            const unsigned u  = __float_as_uint(f);
            const float    hi = __uint_as_float(u & 0xFFFF0000u);
            bh[j] = (short)(u >> 16);
            bl[j] = (short)(__float_as_uint(f - hi) >> 16);
        }
        acc0 = __builtin_amdgcn_mfma_f32_16x16x32_bf16(a0, bh, acc0, 0, 0, 0);
        acc0 = __builtin_amdgcn_mfma_f32_16x16x32_bf16(a0, bl, acc0, 0, 0, 0);
        acc1 = __builtin_amdgcn_mfma_f32_16x16x32_bf16(a1, bh, acc1, 0, 0, 0);
        acc1 = __builtin_amdgcn_mfma_f32_16x16x32_bf16(a1, bl, acc1, 0, 0, 0);
    }

    // Epilogue: C/D layout col=lane&15 (-> dcol), row=quad*4+reg (-> label)
    #pragma unroll
    for (int mt = 0; mt < 2; ++mt) {
        const f32x4 A = mt ? acc1 : acc0;
        #pragma unroll
        for (int r = 0; r < 4; ++r) {
            const int   s = mt * 16 + quad * 4 + r;   // label index 0..31
            const float c = A[r];
            const float v = vgs[((size_t)b * Sx + s) * Dx + dcol];
            float pn = c * v, ps = c * c, pv = v * v;
            #pragma unroll
            for (int off = 1; off < 16; off <<= 1) {  // reduce 16 lanes/quad
                pn += __shfl_xor(pn, off, 64);
                ps += __shfl_xor(ps, off, 64);
                pv += __shfl_xor(pv, off, 64);
            }
            if (m == 0) {
                atomicAdd(&red[s],          pn);
                atomicAdd(&red[Sx + s],     ps);
                atomicAdd(&red[2 * Sx + s], pv);
            }
        }
    }
    __syncthreads();
    if (tid < Sx) {
        pnum[bid * Sx + tid] = red[tid];
        pns2[bid * Sx + tid] = red[Sx + tid];
        pnv2[bid * Sx + tid] = red[2 * Sx + tid];
    }
}

// ---------------------------------------------------------------------------
// Kernel 2: fold the 8 D-chunk partials per (b,s), torch cosine eps
// semantics, reduce to the scalar loss.
//   cos = num / max(||V|| * ||seg_sum||, eps*cnt)
// ---------------------------------------------------------------------------
__global__ __launch_bounds__(256) void finalize_kernel(
    const float* __restrict__ pnum, const float* __restrict__ pns2,
    const float* __restrict__ pnv2, const int* __restrict__ wcnt,
    float* __restrict__ out)
{
    const int tid = threadIdx.x;
    float lsum = 0.0f;
    #pragma unroll
    for (int k = 0; k < (Bx * Sx) / 256; ++k) {   // 8 pairs/thread
        const int p = k * 256 + tid;              // (b,s) flat index
        const int b = p >> 5;
        const int s = p & 31;
        float num = 0.f, ns2 = 0.f, nv2 = 0.f;
        #pragma unroll
        for (int dc = 0; dc < NCH; ++dc) {
            const int idx = (b * NCH + dc) * Sx + s;
            num += pnum[idx];
            ns2 += pns2[idx];
            nv2 += pnv2[idx];
        }
        const float cnt   = (float)wcnt[p];
        const float denom = fmaxf(sqrtf(nv2) * sqrtf(ns2), 1e-8f * cnt);
        lsum += num / denom;
    }
    #pragma unroll
    for (int off = 32; off > 0; off >>= 1) lsum += __shfl_xor(lsum, off, 64);

    __shared__ float red[4];
    if ((tid & 63) == 0) red[tid >> 6] = lsum;
    __syncthreads();
    if (tid == 0) {
        const float total = red[0] + red[1] + red[2] + red[3];
        out[0] = 1.0f - total * (1.0f / (float)(Bx * Sx));
    }
}

// ---------------------------------------------------------------------------
extern "C" void kernel_launch(void* const* d_in, const int* in_sizes, int n_in,
                              void* d_out, int out_size, void* d_ws, size_t ws_size,
                              hipStream_t stream) {
    const int*   attrs = (const int*)d_in[0];
    const float* text  = (const float*)d_in[1];
    const float* vgs   = (const float*)d_in[2];
    float* out = (float*)d_out;

    float* pnum = (float*)d_ws;                 // 512*32 f32 = 64 KB
    float* pns2 = pnum + NBLK * Sx;             // 64 KB
    float* pnv2 = pns2 + NBLK * Sx;             // 64 KB
    int*   wcnt = (int*)(pnv2 + NBLK * Sx);     // 8 KB

    hist_kernel<<<Bx, 1024, 0, stream>>>(attrs, wcnt);
    seg_dot_kernel<<<NBLK, 512, 0, stream>>>(text, vgs, attrs,
                                             pnum, pns2, pnv2);
    finalize_kernel<<<1, 256, 0, stream>>>(pnum, pns2, pnv2, wcnt, out);
}